// Round 4
// baseline (591.393 us; speedup 1.0000x reference)
//
#include <hip/hip_runtime.h>

// Problem constants (from reference setup_inputs): B=4, T=512, U=128, D=512, V=512
#define B_ 4
#define T_ 512
#define U_ 128
#define D_ 512
#define V_ 512
#define MS (B_ * T_)          // 2048 speech rows
#define MT (B_ * U_)          // 512 text rows
#define MTOT (MS + MT)        // 2560
#define LOGITS_ELEMS ((size_t)B_ * T_ * U_ * V_)   // 134217728

// GEMM tiling: 128x64 output tile, 256 threads, 8x4 per thread, K-tile 32,
// K-split x2 via blockIdx.z -> grid 20x8x2 = 320 blocks (proven 561us config).
// LDS holds TRANSPOSED tiles (k-major): a-reads broadcast (conflict-free),
// b-reads 64 consecutive floats (2-way = free).
#define TM 128
#define TN 64
#define TK 32
#define XSTR 132              // Xt row stride (floats): 128 + 4, keeps 16B align
#define WSTR 68               // Wt row stride (floats): 64 + 4

// Partial-region layout (floats): [S (MS*V) | Tx (MT*V)] repeated per z.
#define S_ELEMS ((size_t)MS * V_)          // 1048576
#define TX_ELEMS ((size_t)MT * V_)         // 262144
#define PSTRIDE (S_ELEMS + TX_ELEMS)       // 1310720 floats per partial region
#define PS4 (PSTRIDE / 4)

// bcast t-chunking: each block owns (b, 16 t-rows, 32 u-rows) so Tx/S are read
// ONCE per block (96 MB total, was ~1 GB of L2/L3-thrashed re-reads).
#define TCH 16
#define UCH 32
#define V4_ (V_ / 4)          // 128

typedef float f32x4 __attribute__((ext_vector_type(4)));

// Kernel 1: partial C = X * W[:, kbase:kbase+ktiles*TK]^T slice,
// X = concat(speech [2048,512], text [512,512]).
// Speech rows -> S partial, text rows -> Tx partial (+bias only when kbase==0).
__global__ __launch_bounds__(256, 2) void gemm_joint(
    const float* __restrict__ speech, const float* __restrict__ text,
    const float* __restrict__ W, const float* __restrict__ bias,
    float* __restrict__ S, float* __restrict__ Tx, int ktiles)
{
    __shared__ float Xt[TK][XSTR];   // Xt[k][m]
    __shared__ float Wt[TK][WSTR];   // Wt[k][n]

    const int tid = threadIdx.x;
    const int m0 = blockIdx.x * TM;
    const int n0 = blockIdx.y * TN;
    const int z  = blockIdx.z;
    const int kbase = z * ktiles * TK;
    const int tx = tid & 15;         // n: 16 groups of 4 cols
    const int ty = tid >> 4;         // m: 16 groups of 8 rows

    S  += (size_t)z * PSTRIDE;
    Tx += (size_t)z * PSTRIDE;

    const float* xbase = (m0 < MS) ? (speech + (size_t)m0 * D_)
                                   : (text + (size_t)(m0 - MS) * D_);

    float acc[8][4] = {};
    float4 xr[4], wr[2];

    // ---- prologue: load + transpose-store K-tile 0 of this z-half ----
    #pragma unroll
    for (int i = 0; i < 4; ++i) {
        const int q = tid + 256 * i;                  // 0..1023 float4s of X tile
        xr[i] = *(const float4*)(xbase + (size_t)(q >> 3) * D_ + kbase + ((q & 7) << 2));
    }
    #pragma unroll
    for (int i = 0; i < 2; ++i) {
        const int q = tid + 256 * i;                  // 0..511 float4s of W tile
        wr[i] = *(const float4*)(W + (size_t)(n0 + (q >> 3)) * D_ + kbase + ((q & 7) << 2));
    }
    #pragma unroll
    for (int i = 0; i < 4; ++i) {
        const int q = tid + 256 * i;
        const int r = q >> 3, c = (q & 7) << 2;
        Xt[c + 0][r] = xr[i].x; Xt[c + 1][r] = xr[i].y;
        Xt[c + 2][r] = xr[i].z; Xt[c + 3][r] = xr[i].w;
    }
    #pragma unroll
    for (int i = 0; i < 2; ++i) {
        const int q = tid + 256 * i;
        const int r = q >> 3, c = (q & 7) << 2;
        Wt[c + 0][r] = wr[i].x; Wt[c + 1][r] = wr[i].y;
        Wt[c + 2][r] = wr[i].z; Wt[c + 3][r] = wr[i].w;
    }
    __syncthreads();

    for (int t = 0; t < ktiles; ++t) {
        // register-prefetch the next K-tile across the compute phase
        if (t + 1 < ktiles) {
            const int kn = kbase + (t + 1) * TK;
            #pragma unroll
            for (int i = 0; i < 4; ++i) {
                const int q = tid + 256 * i;
                xr[i] = *(const float4*)(xbase + (size_t)(q >> 3) * D_ + kn + ((q & 7) << 2));
            }
            #pragma unroll
            for (int i = 0; i < 2; ++i) {
                const int q = tid + 256 * i;
                wr[i] = *(const float4*)(W + (size_t)(n0 + (q >> 3)) * D_ + kn + ((q & 7) << 2));
            }
        }

        // outer-product compute over the 32 k of this tile
        #pragma unroll 8
        for (int k = 0; k < TK; ++k) {
            const float4 a0 = *(const float4*)&Xt[k][ty * 8];
            const float4 a1 = *(const float4*)&Xt[k][ty * 8 + 4];
            const float4 b0 = *(const float4*)&Wt[k][tx * 4];
            const float av[8] = {a0.x, a0.y, a0.z, a0.w, a1.x, a1.y, a1.z, a1.w};
            const float bv[4] = {b0.x, b0.y, b0.z, b0.w};
            #pragma unroll
            for (int i = 0; i < 8; ++i)
                #pragma unroll
                for (int j = 0; j < 4; ++j)
                    acc[i][j] += av[i] * bv[j];
        }

        if (t + 1 < ktiles) {
            __syncthreads();   // all reads of old tile done
            #pragma unroll
            for (int i = 0; i < 4; ++i) {
                const int q = tid + 256 * i;
                const int r = q >> 3, c = (q & 7) << 2;
                Xt[c + 0][r] = xr[i].x; Xt[c + 1][r] = xr[i].y;
                Xt[c + 2][r] = xr[i].z; Xt[c + 3][r] = xr[i].w;
            }
            #pragma unroll
            for (int i = 0; i < 2; ++i) {
                const int q = tid + 256 * i;
                const int r = q >> 3, c = (q & 7) << 2;
                Wt[c + 0][r] = wr[i].x; Wt[c + 1][r] = wr[i].y;
                Wt[c + 2][r] = wr[i].z; Wt[c + 3][r] = wr[i].w;
            }
            __syncthreads();   // new tile visible
        }
    }

    // ---- epilogue: float4 stores; fold bias into text rows of the z=0 partial ----
    const int vbase = n0 + tx * 4;
    #pragma unroll
    for (int i = 0; i < 8; ++i) {
        const int m = m0 + ty * 8 + i;
        float4 o;
        o.x = acc[i][0]; o.y = acc[i][1]; o.z = acc[i][2]; o.w = acc[i][3];
        if (m < MS) {
            *(float4*)(S + (size_t)m * V_ + vbase) = o;
        } else {
            if (kbase == 0) {
                o.x += bias[vbase + 0];
                o.y += bias[vbase + 1];
                o.z += bias[vbase + 2];
                o.w += bias[vbase + 3];
            }
            *(float4*)(Tx + (size_t)(m - MS) * V_ + vbase) = o;
        }
    }
}

// Kernel 2: out[b,t,u,v] = S[b*T+t, v] + Tx[b*U+u, v]   (bias already in Tx)
// t-chunked: block = (b, t-chunk of 16, u-quarter of 32). The 16 S values per
// thread live in registers (static indexing); the Tx slice is streamed once.
// Global reads drop ~11x vs the per-(b,t) version whose Tx re-reads missed the
// store-thrashed L2/L3 and went to HBM. Plain stores = the 6.2 TB/s fill path.
// Lens-append folded into block (0,0,0).
template <bool SPLIT>
__global__ __launch_bounds__(256, 2) void bcast_add(
    const float* __restrict__ S, const float* __restrict__ Tx,
    const int* __restrict__ sl, const int* __restrict__ tl,
    float* __restrict__ out)
{
    const int tid = threadIdx.x;
    const int tc = blockIdx.x;      // 0..T_/TCH-1
    const int uq = blockIdx.y;      // 0..U_/UCH-1
    const int b  = blockIdx.z;      // 0..B_-1
    const int t0 = tc * TCH;
    const int u0 = uq * UCH;

    if ((tc | uq | b) == 0 && tid < 2 * B_) {
        out[LOGITS_ELEMS + tid] = (tid < B_) ? (float)sl[tid]
                                             : (float)tl[tid - B_];
    }

    const f32x4* S4 = (const f32x4*)S;
    const f32x4* T4 = (const f32x4*)Tx + ((size_t)b * U_ + u0) * V4_;
    f32x4* O4 = (f32x4*)out + (((size_t)b * T_ + t0) * U_ + u0) * V4_;

    // Per-thread loop-invariant S values: v4 = idx & 127 == tid & 127 always.
    const int v4 = tid & (V4_ - 1);
    f32x4 sv[TCH];
    #pragma unroll
    for (int t = 0; t < TCH; ++t) {
        const size_t si = ((size_t)b * T_ + t0 + t) * V4_ + v4;
        sv[t] = S4[si];
        if (SPLIT) sv[t] += S4[PS4 + si];
    }

    #pragma unroll 2
    for (int idx = tid; idx < UCH * V4_; idx += 256) {
        f32x4 tv = T4[idx];
        if (SPLIT) tv += T4[PS4 + idx];
        #pragma unroll
        for (int t = 0; t < TCH; ++t)
            O4[(size_t)t * (U_ * V4_) + idx] = sv[t] + tv;
    }
}

extern "C" void kernel_launch(void* const* d_in, const int* in_sizes, int n_in,
                              void* d_out, int out_size, void* d_ws, size_t ws_size,
                              hipStream_t stream) {
    const float* speech = (const float*)d_in[0];
    const float* text   = (const float*)d_in[1];
    const float* W      = (const float*)d_in[2];
    const float* bias   = (const float*)d_in[3];
    const int*   sl     = (const int*)d_in[4];
    const int*   tl     = (const int*)d_in[5];
    float* out = (float*)d_out;

    float* S  = (float*)d_ws;                 // partial 0: [S | Tx]
    float* Tx = S + S_ELEMS;                  // partial 1 lives at +PSTRIDE

    const bool split = ws_size >= 2 * PSTRIDE * sizeof(float);
    dim3 g2(T_ / TCH, U_ / UCH, B_);          // 32 x 4 x 4 = 512 blocks

    if (split) {
        dim3 g1(MTOT / TM, V_ / TN, 2);       // 20 x 8 x 2 = 320 blocks
        gemm_joint<<<g1, 256, 0, stream>>>(speech, text, W, bias, S, Tx, (D_ / TK) / 2);
        bcast_add<true><<<g2, 256, 0, stream>>>(S, Tx, sl, tl, out);
    } else {
        dim3 g1(MTOT / TM, V_ / TN, 1);       // fallback: unsplit
        gemm_joint<<<g1, 256, 0, stream>>>(speech, text, W, bias, S, Tx, D_ / TK);
        bcast_add<false><<<g2, 256, 0, stream>>>(S, Tx, sl, tl, out);
    }
}

// Round 5
// 584.492 us; speedup vs baseline: 1.0118x; 1.0118x over previous
//
#include <hip/hip_runtime.h>

// Problem constants (from reference setup_inputs): B=4, T=512, U=128, D=512, V=512
#define B_ 4
#define T_ 512
#define U_ 128
#define D_ 512
#define V_ 512
#define MS (B_ * T_)          // 2048 speech rows
#define MT (B_ * U_)          // 512 text rows
#define MTOT (MS + MT)        // 2560
#define LOGITS_ELEMS ((size_t)B_ * T_ * U_ * V_)   // 134217728

// GEMM tiling: 128x64 output tile, 256 threads, 8x4 per thread, K-tile 32,
// K-split x2 via blockIdx.z -> grid 20x8x2 = 320 blocks (proven 561us config).
// LDS holds TRANSPOSED tiles (k-major): a-reads broadcast (conflict-free),
// b-reads 64 consecutive floats (2-way = free).
#define TM 128
#define TN 64
#define TK 32
#define XSTR 132              // Xt row stride (floats): 128 + 4, keeps 16B align
#define WSTR 68               // Wt row stride (floats): 64 + 4

// Partial-region layout (floats): [S (MS*V) | Tx (MT*V)] repeated per z.
#define S_ELEMS ((size_t)MS * V_)          // 1048576
#define TX_ELEMS ((size_t)MT * V_)         // 262144
#define PSTRIDE (S_ELEMS + TX_ELEMS)       // 1310720 floats per partial region
#define PS4 (PSTRIDE / 4)

#define V4_ (V_ / 4)          // 128

typedef float f32x4 __attribute__((ext_vector_type(4)));

// Kernel 1: partial C = X * W[:, kbase:kbase+ktiles*TK]^T slice,
// X = concat(speech [2048,512], text [512,512]).
// Speech rows -> S partial, text rows -> Tx partial (+bias only when kbase==0).
__global__ __launch_bounds__(256, 2) void gemm_joint(
    const float* __restrict__ speech, const float* __restrict__ text,
    const float* __restrict__ W, const float* __restrict__ bias,
    float* __restrict__ S, float* __restrict__ Tx, int ktiles)
{
    __shared__ float Xt[TK][XSTR];   // Xt[k][m]
    __shared__ float Wt[TK][WSTR];   // Wt[k][n]

    const int tid = threadIdx.x;
    const int m0 = blockIdx.x * TM;
    const int n0 = blockIdx.y * TN;
    const int z  = blockIdx.z;
    const int kbase = z * ktiles * TK;
    const int tx = tid & 15;         // n: 16 groups of 4 cols
    const int ty = tid >> 4;         // m: 16 groups of 8 rows

    S  += (size_t)z * PSTRIDE;
    Tx += (size_t)z * PSTRIDE;

    const float* xbase = (m0 < MS) ? (speech + (size_t)m0 * D_)
                                   : (text + (size_t)(m0 - MS) * D_);

    float acc[8][4] = {};
    float4 xr[4], wr[2];

    // ---- prologue: load + transpose-store K-tile 0 of this z-half ----
    #pragma unroll
    for (int i = 0; i < 4; ++i) {
        const int q = tid + 256 * i;                  // 0..1023 float4s of X tile
        xr[i] = *(const float4*)(xbase + (size_t)(q >> 3) * D_ + kbase + ((q & 7) << 2));
    }
    #pragma unroll
    for (int i = 0; i < 2; ++i) {
        const int q = tid + 256 * i;                  // 0..511 float4s of W tile
        wr[i] = *(const float4*)(W + (size_t)(n0 + (q >> 3)) * D_ + kbase + ((q & 7) << 2));
    }
    #pragma unroll
    for (int i = 0; i < 4; ++i) {
        const int q = tid + 256 * i;
        const int r = q >> 3, c = (q & 7) << 2;
        Xt[c + 0][r] = xr[i].x; Xt[c + 1][r] = xr[i].y;
        Xt[c + 2][r] = xr[i].z; Xt[c + 3][r] = xr[i].w;
    }
    #pragma unroll
    for (int i = 0; i < 2; ++i) {
        const int q = tid + 256 * i;
        const int r = q >> 3, c = (q & 7) << 2;
        Wt[c + 0][r] = wr[i].x; Wt[c + 1][r] = wr[i].y;
        Wt[c + 2][r] = wr[i].z; Wt[c + 3][r] = wr[i].w;
    }
    __syncthreads();

    for (int t = 0; t < ktiles; ++t) {
        // register-prefetch the next K-tile across the compute phase
        if (t + 1 < ktiles) {
            const int kn = kbase + (t + 1) * TK;
            #pragma unroll
            for (int i = 0; i < 4; ++i) {
                const int q = tid + 256 * i;
                xr[i] = *(const float4*)(xbase + (size_t)(q >> 3) * D_ + kn + ((q & 7) << 2));
            }
            #pragma unroll
            for (int i = 0; i < 2; ++i) {
                const int q = tid + 256 * i;
                wr[i] = *(const float4*)(W + (size_t)(n0 + (q >> 3)) * D_ + kn + ((q & 7) << 2));
            }
        }

        // outer-product compute over the 32 k of this tile
        #pragma unroll 8
        for (int k = 0; k < TK; ++k) {
            const float4 a0 = *(const float4*)&Xt[k][ty * 8];
            const float4 a1 = *(const float4*)&Xt[k][ty * 8 + 4];
            const float4 b0 = *(const float4*)&Wt[k][tx * 4];
            const float av[8] = {a0.x, a0.y, a0.z, a0.w, a1.x, a1.y, a1.z, a1.w};
            const float bv[4] = {b0.x, b0.y, b0.z, b0.w};
            #pragma unroll
            for (int i = 0; i < 8; ++i)
                #pragma unroll
                for (int j = 0; j < 4; ++j)
                    acc[i][j] += av[i] * bv[j];
        }

        if (t + 1 < ktiles) {
            __syncthreads();   // all reads of old tile done
            #pragma unroll
            for (int i = 0; i < 4; ++i) {
                const int q = tid + 256 * i;
                const int r = q >> 3, c = (q & 7) << 2;
                Xt[c + 0][r] = xr[i].x; Xt[c + 1][r] = xr[i].y;
                Xt[c + 2][r] = xr[i].z; Xt[c + 3][r] = xr[i].w;
            }
            #pragma unroll
            for (int i = 0; i < 2; ++i) {
                const int q = tid + 256 * i;
                const int r = q >> 3, c = (q & 7) << 2;
                Wt[c + 0][r] = wr[i].x; Wt[c + 1][r] = wr[i].y;
                Wt[c + 2][r] = wr[i].z; Wt[c + 3][r] = wr[i].w;
            }
            __syncthreads();   // new tile visible
        }
    }

    // ---- epilogue: float4 stores; fold bias into text rows of the z=0 partial ----
    const int vbase = n0 + tx * 4;
    #pragma unroll
    for (int i = 0; i < 8; ++i) {
        const int m = m0 + ty * 8 + i;
        float4 o;
        o.x = acc[i][0]; o.y = acc[i][1]; o.z = acc[i][2]; o.w = acc[i][3];
        if (m < MS) {
            *(float4*)(S + (size_t)m * V_ + vbase) = o;
        } else {
            if (kbase == 0) {
                o.x += bias[vbase + 0];
                o.y += bias[vbase + 1];
                o.z += bias[vbase + 2];
                o.w += bias[vbase + 3];
            }
            *(float4*)(Tx + (size_t)(m - MS) * V_ + vbase) = o;
        }
    }
}

// Kernel 2: out[b,t,u,v] = S[b*T+t, v] + Tx[b*U+u, v]   (bias already in Tx)
// Structure identical to the proven 561us version (one block per (b,t),
// contiguous 256KB NT-store stream, lens folded into block 0) with ONE change:
// XCD-affinity block swizzle. Hardware maps block bid to XCD bid%8; we choose
// (b,t) from bid so batch b's blocks land only on XCDs {2b,2b+1}. Each XCD's
// Tx working set is then one batch's 512KB (both partials) -> guaranteed
// L2-resident under the 537MB store stream, instead of every XCD juggling all
// 4 batches (2MB) with partial eviction to L3/HBM.
//   xcd = bid & 7;  b = xcd >> 1;  t = ((bid >> 3) << 1) | (xcd & 1)
// (bijective over bid in [0,2048): for fixed b, xcd&1 + bid>>3 cover all t).
template <bool SPLIT>
__global__ __launch_bounds__(256, 8) void bcast_add(
    const float* __restrict__ S, const float* __restrict__ Tx,
    const int* __restrict__ sl, const int* __restrict__ tl,
    float* __restrict__ out)
{
    const int V4 = V4_;                     // 128
    const int bid = blockIdx.x;             // 0..2047
    const int xcd = bid & 7;
    const int b   = xcd >> 1;               // batch pinned to an XCD pair
    const int t   = ((bid >> 3) << 1) | (xcd & 1);
    const int bt  = (b << 9) | t;           // b*T_ + t
    const int tid = threadIdx.x;

    if (bt == 0 && tid < 2 * B_) {          // bid==0 -> b=0,t=0: exactly one block
        out[LOGITS_ELEMS + tid] = (tid < B_) ? (float)sl[tid]
                                             : (float)tl[tid - B_];
    }

    const f32x4* S4 = (const f32x4*)S + (size_t)bt * V4;
    const f32x4* T4 = (const f32x4*)Tx + (size_t)b * U_ * V4;
    f32x4* O4 = (f32x4*)out + (size_t)bt * U_ * V4;

    // idx % 128 == tid % 128 for every iteration -> S row element is loop-invariant
    f32x4 sv = S4[tid & (V4 - 1)];
    if (SPLIT) sv += S4[PS4 + (tid & (V4 - 1))];

    #pragma unroll 8
    for (int idx = tid; idx < U_ * V4; idx += 256) {
        f32x4 tv = T4[idx];
        if (SPLIT) tv += T4[PS4 + idx];
        __builtin_nontemporal_store(sv + tv, &O4[idx]);
    }
}

extern "C" void kernel_launch(void* const* d_in, const int* in_sizes, int n_in,
                              void* d_out, int out_size, void* d_ws, size_t ws_size,
                              hipStream_t stream) {
    const float* speech = (const float*)d_in[0];
    const float* text   = (const float*)d_in[1];
    const float* W      = (const float*)d_in[2];
    const float* bias   = (const float*)d_in[3];
    const int*   sl     = (const int*)d_in[4];
    const int*   tl     = (const int*)d_in[5];
    float* out = (float*)d_out;

    float* S  = (float*)d_ws;                 // partial 0: [S | Tx]
    float* Tx = S + S_ELEMS;                  // partial 1 lives at +PSTRIDE

    const bool split = ws_size >= 2 * PSTRIDE * sizeof(float);

    if (split) {
        dim3 g1(MTOT / TM, V_ / TN, 2);       // 20 x 8 x 2 = 320 blocks
        gemm_joint<<<g1, 256, 0, stream>>>(speech, text, W, bias, S, Tx, (D_ / TK) / 2);
        bcast_add<true><<<MS, 256, 0, stream>>>(S, Tx, sl, tl, out);
    } else {
        dim3 g1(MTOT / TM, V_ / TN, 1);       // fallback: unsplit
        gemm_joint<<<g1, 256, 0, stream>>>(speech, text, W, bias, S, Tx, D_ / TK);
        bcast_add<false><<<MS, 256, 0, stream>>>(S, Tx, sl, tl, out);
    }
}

// Round 6
// 574.774 us; speedup vs baseline: 1.0289x; 1.0169x over previous
//
#include <hip/hip_runtime.h>

// Problem constants (from reference setup_inputs): B=4, T=512, U=128, D=512, V=512
#define B_ 4
#define T_ 512
#define U_ 128
#define D_ 512
#define V_ 512
#define MS (B_ * T_)          // 2048 speech rows
#define MT (B_ * U_)          // 512 text rows
#define MTOT (MS + MT)        // 2560
#define LOGITS_ELEMS ((size_t)B_ * T_ * U_ * V_)   // 134217728

// GEMM tiling: 128x64 output tile, 256 threads, 8x4 per thread, K-tile 32,
// K-split x2 via blockIdx.z -> grid 20x8x2 = 320 blocks (proven 561us config,
// byte-identical to R3).  LDS holds TRANSPOSED tiles (k-major): a-reads
// broadcast (conflict-free), b-reads 64 consecutive floats (2-way = free).
#define TM 128
#define TN 64
#define TK 32
#define XSTR 132              // Xt row stride (floats): 128 + 4, keeps 16B align
#define WSTR 68               // Wt row stride (floats): 64 + 4

// Partial-region layout (floats): [S (MS*V) | Tx (MT*V)] repeated per z.
#define S_ELEMS ((size_t)MS * V_)          // 1048576
#define TX_ELEMS ((size_t)MT * V_)         // 262144
#define PSTRIDE (S_ELEMS + TX_ELEMS)       // 1310720 floats per partial region
#define PS4 (PSTRIDE / 4)

#define V4_ (V_ / 4)          // 128

// bcast t-chunk: 4 consecutive t-rows per block. Output region per block is
// CONTIGUOUS 1MB; consecutive blocks write consecutive regions (preserves the
// R3 store ordering the HW likes -- R4's 16-way u-split scatter and R5's XCD
// swizzle both regressed). Per-CU concurrent write streams: 4/block x 2
// blocks/CU = 8, same as R3's 1 x 8. Tx re-read factor drops 512 -> 128.
#define TCH 4

typedef float f32x4 __attribute__((ext_vector_type(4)));

// Kernel 1: partial C = X * W[:, kbase:kbase+ktiles*TK]^T slice,
// X = concat(speech [2048,512], text [512,512]).
// Speech rows -> S partial, text rows -> Tx partial (+bias only when kbase==0).
__global__ __launch_bounds__(256, 2) void gemm_joint(
    const float* __restrict__ speech, const float* __restrict__ text,
    const float* __restrict__ W, const float* __restrict__ bias,
    float* __restrict__ S, float* __restrict__ Tx, int ktiles)
{
    __shared__ float Xt[TK][XSTR];   // Xt[k][m]
    __shared__ float Wt[TK][WSTR];   // Wt[k][n]

    const int tid = threadIdx.x;
    const int m0 = blockIdx.x * TM;
    const int n0 = blockIdx.y * TN;
    const int z  = blockIdx.z;
    const int kbase = z * ktiles * TK;
    const int tx = tid & 15;         // n: 16 groups of 4 cols
    const int ty = tid >> 4;         // m: 16 groups of 8 rows

    S  += (size_t)z * PSTRIDE;
    Tx += (size_t)z * PSTRIDE;

    const float* xbase = (m0 < MS) ? (speech + (size_t)m0 * D_)
                                   : (text + (size_t)(m0 - MS) * D_);

    float acc[8][4] = {};
    float4 xr[4], wr[2];

    // ---- prologue: load + transpose-store K-tile 0 of this z-half ----
    #pragma unroll
    for (int i = 0; i < 4; ++i) {
        const int q = tid + 256 * i;                  // 0..1023 float4s of X tile
        xr[i] = *(const float4*)(xbase + (size_t)(q >> 3) * D_ + kbase + ((q & 7) << 2));
    }
    #pragma unroll
    for (int i = 0; i < 2; ++i) {
        const int q = tid + 256 * i;                  // 0..511 float4s of W tile
        wr[i] = *(const float4*)(W + (size_t)(n0 + (q >> 3)) * D_ + kbase + ((q & 7) << 2));
    }
    #pragma unroll
    for (int i = 0; i < 4; ++i) {
        const int q = tid + 256 * i;
        const int r = q >> 3, c = (q & 7) << 2;
        Xt[c + 0][r] = xr[i].x; Xt[c + 1][r] = xr[i].y;
        Xt[c + 2][r] = xr[i].z; Xt[c + 3][r] = xr[i].w;
    }
    #pragma unroll
    for (int i = 0; i < 2; ++i) {
        const int q = tid + 256 * i;
        const int r = q >> 3, c = (q & 7) << 2;
        Wt[c + 0][r] = wr[i].x; Wt[c + 1][r] = wr[i].y;
        Wt[c + 2][r] = wr[i].z; Wt[c + 3][r] = wr[i].w;
    }
    __syncthreads();

    for (int t = 0; t < ktiles; ++t) {
        // register-prefetch the next K-tile across the compute phase
        if (t + 1 < ktiles) {
            const int kn = kbase + (t + 1) * TK;
            #pragma unroll
            for (int i = 0; i < 4; ++i) {
                const int q = tid + 256 * i;
                xr[i] = *(const float4*)(xbase + (size_t)(q >> 3) * D_ + kn + ((q & 7) << 2));
            }
            #pragma unroll
            for (int i = 0; i < 2; ++i) {
                const int q = tid + 256 * i;
                wr[i] = *(const float4*)(W + (size_t)(n0 + (q >> 3)) * D_ + kn + ((q & 7) << 2));
            }
        }

        // outer-product compute over the 32 k of this tile
        #pragma unroll 8
        for (int k = 0; k < TK; ++k) {
            const float4 a0 = *(const float4*)&Xt[k][ty * 8];
            const float4 a1 = *(const float4*)&Xt[k][ty * 8 + 4];
            const float4 b0 = *(const float4*)&Wt[k][tx * 4];
            const float av[8] = {a0.x, a0.y, a0.z, a0.w, a1.x, a1.y, a1.z, a1.w};
            const float bv[4] = {b0.x, b0.y, b0.z, b0.w};
            #pragma unroll
            for (int i = 0; i < 8; ++i)
                #pragma unroll
                for (int j = 0; j < 4; ++j)
                    acc[i][j] += av[i] * bv[j];
        }

        if (t + 1 < ktiles) {
            __syncthreads();   // all reads of old tile done
            #pragma unroll
            for (int i = 0; i < 4; ++i) {
                const int q = tid + 256 * i;
                const int r = q >> 3, c = (q & 7) << 2;
                Xt[c + 0][r] = xr[i].x; Xt[c + 1][r] = xr[i].y;
                Xt[c + 2][r] = xr[i].z; Xt[c + 3][r] = xr[i].w;
            }
            #pragma unroll
            for (int i = 0; i < 2; ++i) {
                const int q = tid + 256 * i;
                const int r = q >> 3, c = (q & 7) << 2;
                Wt[c + 0][r] = wr[i].x; Wt[c + 1][r] = wr[i].y;
                Wt[c + 2][r] = wr[i].z; Wt[c + 3][r] = wr[i].w;
            }
            __syncthreads();   // new tile visible
        }
    }

    // ---- epilogue: float4 stores; fold bias into text rows of the z=0 partial ----
    const int vbase = n0 + tx * 4;
    #pragma unroll
    for (int i = 0; i < 8; ++i) {
        const int m = m0 + ty * 8 + i;
        float4 o;
        o.x = acc[i][0]; o.y = acc[i][1]; o.z = acc[i][2]; o.w = acc[i][3];
        if (m < MS) {
            *(float4*)(S + (size_t)m * V_ + vbase) = o;
        } else {
            if (kbase == 0) {
                o.x += bias[vbase + 0];
                o.y += bias[vbase + 1];
                o.z += bias[vbase + 2];
                o.w += bias[vbase + 3];
            }
            *(float4*)(Tx + (size_t)(m - MS) * V_ + vbase) = o;
        }
    }
}

// Kernel 2: out[b,t,u,v] = S[b*T+t, v] + Tx[b*U+u, v]   (bias already in Tx)
// One block per (b, 4-t-chunk): reads the batch's Tx slice once per block
// (re-read factor 512 -> 128; ~800MB less HBM read traffic) and NT-streams a
// contiguous 1MB output region.  sv[TCH] is statically indexed (stays in
// registers).  Sequential bid -> sequential addresses, no swizzle (R5 lesson).
// Lens-append folded into block 0.
template <bool SPLIT>
__global__ __launch_bounds__(256, 2) void bcast_add(
    const float* __restrict__ S, const float* __restrict__ Tx,
    const int* __restrict__ sl, const int* __restrict__ tl,
    float* __restrict__ out)
{
    const int tid = threadIdx.x;
    const int blk = blockIdx.x;              // 0..511
    const int tpb = T_ / TCH;                // 128 t-chunks per batch
    const int b   = blk >> 7;                // blk / tpb
    const int t0  = (blk & (tpb - 1)) * TCH;

    if (blk == 0 && tid < 2 * B_) {
        out[LOGITS_ELEMS + tid] = (tid < B_) ? (float)sl[tid]
                                             : (float)tl[tid - B_];
    }

    const f32x4* S4 = (const f32x4*)S;
    const f32x4* T4 = (const f32x4*)Tx + (size_t)b * U_ * V4_;
    f32x4* O4 = (f32x4*)out + ((size_t)b * T_ + t0) * U_ * V4_;

    // Per-thread loop-invariant S values: idx & 127 == tid & 127 always.
    const int v4 = tid & (V4_ - 1);
    f32x4 sv[TCH];
    #pragma unroll
    for (int t = 0; t < TCH; ++t) {
        const size_t si = ((size_t)b * T_ + t0 + t) * V4_ + v4;
        sv[t] = S4[si];
        if (SPLIT) sv[t] += S4[PS4 + si];
    }

    #pragma unroll 4
    for (int idx = tid; idx < U_ * V4_; idx += 256) {
        f32x4 tv = T4[idx];
        if (SPLIT) tv += T4[PS4 + idx];
        #pragma unroll
        for (int t = 0; t < TCH; ++t)
            __builtin_nontemporal_store(sv[t] + tv,
                                        &O4[(size_t)t * (U_ * V4_) + idx]);
    }
}

extern "C" void kernel_launch(void* const* d_in, const int* in_sizes, int n_in,
                              void* d_out, int out_size, void* d_ws, size_t ws_size,
                              hipStream_t stream) {
    const float* speech = (const float*)d_in[0];
    const float* text   = (const float*)d_in[1];
    const float* W      = (const float*)d_in[2];
    const float* bias   = (const float*)d_in[3];
    const int*   sl     = (const int*)d_in[4];
    const int*   tl     = (const int*)d_in[5];
    float* out = (float*)d_out;

    float* S  = (float*)d_ws;                 // partial 0: [S | Tx]
    float* Tx = S + S_ELEMS;                  // partial 1 lives at +PSTRIDE

    const bool split = ws_size >= 2 * PSTRIDE * sizeof(float);
    const int nblk2 = MS / TCH;               // 512 blocks

    if (split) {
        dim3 g1(MTOT / TM, V_ / TN, 2);       // 20 x 8 x 2 = 320 blocks
        gemm_joint<<<g1, 256, 0, stream>>>(speech, text, W, bias, S, Tx, (D_ / TK) / 2);
        bcast_add<true><<<nblk2, 256, 0, stream>>>(S, Tx, sl, tl, out);
    } else {
        dim3 g1(MTOT / TM, V_ / TN, 1);       // fallback: unsplit
        gemm_joint<<<g1, 256, 0, stream>>>(speech, text, W, bias, S, Tx, D_ / TK);
        bcast_add<false><<<nblk2, 256, 0, stream>>>(S, Tx, sl, tl, out);
    }
}

// Round 7
// 559.591 us; speedup vs baseline: 1.0568x; 1.0271x over previous
//
#include <hip/hip_runtime.h>

// Problem constants (from reference setup_inputs): B=4, T=512, U=128, D=512, V=512
#define B_ 4
#define T_ 512
#define U_ 128
#define D_ 512
#define V_ 512
#define MS (B_ * T_)          // 2048 speech rows
#define MT (B_ * U_)          // 512 text rows
#define MTOT (MS + MT)        // 2560
#define LOGITS_ELEMS ((size_t)B_ * T_ * U_ * V_)   // 134217728

// GEMM tiling: 128x64 output tile, 256 threads, 8x4 per thread, K-tile 32,
// K-split x2 via blockIdx.z -> grid 20x8x2 = 320 blocks (proven 561us config).
// LDS holds TRANSPOSED tiles (k-major): a-reads broadcast (conflict-free),
// b-reads 64 consecutive floats (2-way = free).
// NOTE: this is a byte-identical revert to the round-3 kernel (561us), the
// best measured configuration. R4 (u-scatter writes), R5 (XCD swizzle) and
// R6 (t-chunk=4) each regressed: Tx re-reads are L2-hits (2MB/XCD vs 4MB L2,
// NT stores don't allocate) so read-locality changes buy nothing, while any
// deviation from sequential-bid -> contiguous-256KB write ordering costs
// +14..30us on the HBM write path.
#define TM 128
#define TN 64
#define TK 32
#define XSTR 132              // Xt row stride (floats): 128 + 4, keeps 16B align
#define WSTR 68               // Wt row stride (floats): 64 + 4

// Partial-region layout (floats): [S (MS*V) | Tx (MT*V)] repeated per z.
#define S_ELEMS ((size_t)MS * V_)          // 1048576
#define TX_ELEMS ((size_t)MT * V_)         // 262144
#define PSTRIDE (S_ELEMS + TX_ELEMS)       // 1310720 floats per partial region
#define PS4 (PSTRIDE / 4)

typedef float f32x4 __attribute__((ext_vector_type(4)));

// Kernel 1: partial C = X * W[:, kbase:kbase+ktiles*TK]^T slice,
// X = concat(speech [2048,512], text [512,512]).
// Speech rows -> S partial, text rows -> Tx partial (+bias only when kbase==0).
__global__ __launch_bounds__(256, 2) void gemm_joint(
    const float* __restrict__ speech, const float* __restrict__ text,
    const float* __restrict__ W, const float* __restrict__ bias,
    float* __restrict__ S, float* __restrict__ Tx, int ktiles)
{
    __shared__ float Xt[TK][XSTR];   // Xt[k][m]
    __shared__ float Wt[TK][WSTR];   // Wt[k][n]

    const int tid = threadIdx.x;
    const int m0 = blockIdx.x * TM;
    const int n0 = blockIdx.y * TN;
    const int z  = blockIdx.z;
    const int kbase = z * ktiles * TK;
    const int tx = tid & 15;         // n: 16 groups of 4 cols
    const int ty = tid >> 4;         // m: 16 groups of 8 rows

    S  += (size_t)z * PSTRIDE;
    Tx += (size_t)z * PSTRIDE;

    const float* xbase = (m0 < MS) ? (speech + (size_t)m0 * D_)
                                   : (text + (size_t)(m0 - MS) * D_);

    float acc[8][4] = {};
    float4 xr[4], wr[2];

    // ---- prologue: load + transpose-store K-tile 0 of this z-half ----
    #pragma unroll
    for (int i = 0; i < 4; ++i) {
        const int q = tid + 256 * i;                  // 0..1023 float4s of X tile
        xr[i] = *(const float4*)(xbase + (size_t)(q >> 3) * D_ + kbase + ((q & 7) << 2));
    }
    #pragma unroll
    for (int i = 0; i < 2; ++i) {
        const int q = tid + 256 * i;                  // 0..511 float4s of W tile
        wr[i] = *(const float4*)(W + (size_t)(n0 + (q >> 3)) * D_ + kbase + ((q & 7) << 2));
    }
    #pragma unroll
    for (int i = 0; i < 4; ++i) {
        const int q = tid + 256 * i;
        const int r = q >> 3, c = (q & 7) << 2;
        Xt[c + 0][r] = xr[i].x; Xt[c + 1][r] = xr[i].y;
        Xt[c + 2][r] = xr[i].z; Xt[c + 3][r] = xr[i].w;
    }
    #pragma unroll
    for (int i = 0; i < 2; ++i) {
        const int q = tid + 256 * i;
        const int r = q >> 3, c = (q & 7) << 2;
        Wt[c + 0][r] = wr[i].x; Wt[c + 1][r] = wr[i].y;
        Wt[c + 2][r] = wr[i].z; Wt[c + 3][r] = wr[i].w;
    }
    __syncthreads();

    for (int t = 0; t < ktiles; ++t) {
        // register-prefetch the next K-tile across the compute phase
        if (t + 1 < ktiles) {
            const int kn = kbase + (t + 1) * TK;
            #pragma unroll
            for (int i = 0; i < 4; ++i) {
                const int q = tid + 256 * i;
                xr[i] = *(const float4*)(xbase + (size_t)(q >> 3) * D_ + kn + ((q & 7) << 2));
            }
            #pragma unroll
            for (int i = 0; i < 2; ++i) {
                const int q = tid + 256 * i;
                wr[i] = *(const float4*)(W + (size_t)(n0 + (q >> 3)) * D_ + kn + ((q & 7) << 2));
            }
        }

        // outer-product compute over the 32 k of this tile
        #pragma unroll 8
        for (int k = 0; k < TK; ++k) {
            const float4 a0 = *(const float4*)&Xt[k][ty * 8];
            const float4 a1 = *(const float4*)&Xt[k][ty * 8 + 4];
            const float4 b0 = *(const float4*)&Wt[k][tx * 4];
            const float av[8] = {a0.x, a0.y, a0.z, a0.w, a1.x, a1.y, a1.z, a1.w};
            const float bv[4] = {b0.x, b0.y, b0.z, b0.w};
            #pragma unroll
            for (int i = 0; i < 8; ++i)
                #pragma unroll
                for (int j = 0; j < 4; ++j)
                    acc[i][j] += av[i] * bv[j];
        }

        if (t + 1 < ktiles) {
            __syncthreads();   // all reads of old tile done
            #pragma unroll
            for (int i = 0; i < 4; ++i) {
                const int q = tid + 256 * i;
                const int r = q >> 3, c = (q & 7) << 2;
                Xt[c + 0][r] = xr[i].x; Xt[c + 1][r] = xr[i].y;
                Xt[c + 2][r] = xr[i].z; Xt[c + 3][r] = xr[i].w;
            }
            #pragma unroll
            for (int i = 0; i < 2; ++i) {
                const int q = tid + 256 * i;
                const int r = q >> 3, c = (q & 7) << 2;
                Wt[c + 0][r] = wr[i].x; Wt[c + 1][r] = wr[i].y;
                Wt[c + 2][r] = wr[i].z; Wt[c + 3][r] = wr[i].w;
            }
            __syncthreads();   // new tile visible
        }
    }

    // ---- epilogue: float4 stores; fold bias into text rows of the z=0 partial ----
    const int vbase = n0 + tx * 4;
    #pragma unroll
    for (int i = 0; i < 8; ++i) {
        const int m = m0 + ty * 8 + i;
        float4 o;
        o.x = acc[i][0]; o.y = acc[i][1]; o.z = acc[i][2]; o.w = acc[i][3];
        if (m < MS) {
            *(float4*)(S + (size_t)m * V_ + vbase) = o;
        } else {
            if (kbase == 0) {
                o.x += bias[vbase + 0];
                o.y += bias[vbase + 1];
                o.z += bias[vbase + 2];
                o.w += bias[vbase + 3];
            }
            *(float4*)(Tx + (size_t)(m - MS) * V_ + vbase) = o;
        }
    }
}

// Kernel 2: out[b,t,u,v] = S[b*T+t, v] + Tx[b*U+u, v]   (bias already in Tx)
// One block per (b,t): writes a contiguous 256KB region. Non-temporal stores
// keep the 537MB stream from allocating in L2 (Tx stays resident; reads hit).
// SPLIT variant sums the two K-partials. Lens-append folded into block 0.
// Sequential bid -> sequential output addresses: the store ordering the HW
// write path rewards (R4/R5/R6 all broke it and regressed).
template <bool SPLIT>
__global__ __launch_bounds__(256, 8) void bcast_add(
    const float* __restrict__ S, const float* __restrict__ Tx,
    const int* __restrict__ sl, const int* __restrict__ tl,
    float* __restrict__ out)
{
    const int V4 = V_ / 4;                  // 128
    const int bt = blockIdx.x;              // 0..2047
    const int b  = bt >> 9;                 // bt / T_
    const int tid = threadIdx.x;

    if (bt == 0 && tid < 2 * B_) {
        out[LOGITS_ELEMS + tid] = (tid < B_) ? (float)sl[tid]
                                             : (float)tl[tid - B_];
    }

    const f32x4* S4 = (const f32x4*)S + (size_t)bt * V4;
    const f32x4* T4 = (const f32x4*)Tx + (size_t)b * U_ * V4;
    f32x4* O4 = (f32x4*)out + (size_t)bt * U_ * V4;

    // idx % 128 == tid % 128 for every iteration -> S row element is loop-invariant
    f32x4 sv = S4[tid & (V4 - 1)];
    if (SPLIT) sv += S4[PS4 + (tid & (V4 - 1))];

    #pragma unroll 8
    for (int idx = tid; idx < U_ * V4; idx += 256) {
        f32x4 tv = T4[idx];
        if (SPLIT) tv += T4[PS4 + idx];
        __builtin_nontemporal_store(sv + tv, &O4[idx]);
    }
}

extern "C" void kernel_launch(void* const* d_in, const int* in_sizes, int n_in,
                              void* d_out, int out_size, void* d_ws, size_t ws_size,
                              hipStream_t stream) {
    const float* speech = (const float*)d_in[0];
    const float* text   = (const float*)d_in[1];
    const float* W      = (const float*)d_in[2];
    const float* bias   = (const float*)d_in[3];
    const int*   sl     = (const int*)d_in[4];
    const int*   tl     = (const int*)d_in[5];
    float* out = (float*)d_out;

    float* S  = (float*)d_ws;                 // partial 0: [S | Tx]
    float* Tx = S + S_ELEMS;                  // partial 1 lives at +PSTRIDE

    const bool split = ws_size >= 2 * PSTRIDE * sizeof(float);

    if (split) {
        dim3 g1(MTOT / TM, V_ / TN, 2);       // 20 x 8 x 2 = 320 blocks
        gemm_joint<<<g1, 256, 0, stream>>>(speech, text, W, bias, S, Tx, (D_ / TK) / 2);
        bcast_add<true><<<MS, 256, 0, stream>>>(S, Tx, sl, tl, out);
    } else {
        dim3 g1(MTOT / TM, V_ / TN, 1);       // fallback: unsplit
        gemm_joint<<<g1, 256, 0, stream>>>(speech, text, W, bias, S, Tx, D_ / TK);
        bcast_add<false><<<MS, 256, 0, stream>>>(S, Tx, sl, tl, out);
    }
}